// Round 4
// baseline (442.532 us; speedup 1.0000x reference)
//
#include <hip/hip_runtime.h>
#include <hip/hip_cooperative_groups.h>

namespace cg = cooperative_groups;

#define NB 32
#define NN 500
#define HIN 64
#define HHID 16
#define NHEAD 8
#define NVALID 400
#define MAXK 128
#define NEG_INF -1e20f
#define GRID 256
#define BLK 512

union SMem {
    struct { int nb[8][MAXK]; float p[8][NHEAD][MAXK]; float inv[8][NHEAD]; } a1;  // 36.5 KB
    struct { int nb[8][MAXK]; float p[8][MAXK]; } a2;                              // 8 KB
    struct { float attn[NN]; float red[8]; float part[8][64]; } pl;                // 4 KB
};

__global__ __launch_bounds__(BLK, 2) void k_fused(
    const float* __restrict__ x, const float* __restrict__ A,
    const float* __restrict__ w1, const float* __restrict__ as1, const float* __restrict__ ad1,
    const float* __restrict__ w2, const float* __restrict__ as2, const float* __restrict__ ad2,
    const float* __restrict__ aw,
    int* __restrict__ nbr, int* __restrict__ cnt,
    float* __restrict__ h1p, float* __restrict__ e1s, float* __restrict__ e1d,
    float* __restrict__ h1cat, float* __restrict__ h2p,
    float* __restrict__ e2s, float* __restrict__ e2d,
    float* __restrict__ xc, float* __restrict__ sc, float* __restrict__ rootd,
    float* __restrict__ out)
{
    cg::grid_group gg = cg::this_grid();
    int t = threadIdx.x, wv = t >> 6, lane = t & 63;
    __shared__ SMem sm;

    // ---------- phase 1: neighbor-list build (wave per row, ballot compaction) ----------
    for (int row = blockIdx.x * 8 + wv; row < NB * NN; row += GRID * 8) {
        const float* ar = A + (size_t)row * NN;
        int c = 0;
        for (int it = 0; it < 8; ++it) {
            int m = it * 64 + lane;
            bool v = (m < NN) && (ar[m] > 0.f);
            unsigned long long bal = __ballot(v);
            if (v) {
                int pos = c + __popcll(bal & ((1ull << lane) - 1ull));
                if (pos < MAXK) nbr[(size_t)row * MAXK + pos] = m;
            }
            c += (int)__popcll(bal);
        }
        if (lane == 0) cnt[row] = c < MAXK ? c : MAXK;
    }
    gg.sync();

    // ---------- phase 2: layer-1 projection + e_src1/e_dst1 (128-thr group per (b,chunk16)) ----------
    {
        int g = t >> 7, gl = t & 127;
        int unit = blockIdx.x * 4 + g;            // exactly 1024 units
        int b = unit >> 5, chunk = unit & 31;
        int h = (gl >> 4) & 7, o = gl & 15;
        float wreg[64];
#pragma unroll
        for (int f = 0; f < 64; ++f) wreg[f] = w1[h * 1024 + f * 16 + o];
        float as_r = as1[h * 16 + o], ad_r = ad1[h * 16 + o];
        for (int i = 0; i < 16; ++i) {
            int n = chunk * 16 + i;
            if (n >= NN) break;                    // uniform within group
            const float4* xp = (const float4*)(x + (size_t)(b * NN + n) * HIN);
            float a0 = 0.f, a1 = 0.f;
#pragma unroll
            for (int f4 = 0; f4 < 16; f4 += 2) {
                float4 u = xp[f4], v = xp[f4 + 1];
                a0 += u.x * wreg[f4 * 4] + u.y * wreg[f4 * 4 + 1] + u.z * wreg[f4 * 4 + 2] + u.w * wreg[f4 * 4 + 3];
                a1 += v.x * wreg[f4 * 4 + 4] + v.y * wreg[f4 * 4 + 5] + v.z * wreg[f4 * 4 + 6] + v.w * wreg[f4 * 4 + 7];
            }
            float acc = a0 + a1;
            h1p[((size_t)(b * NHEAD + h) * NN + n) * HHID + o] = acc;
            float vs = acc * as_r, vd = acc * ad_r;
#pragma unroll
            for (int m = 1; m < 16; m <<= 1) { vs += __shfl_xor(vs, m); vd += __shfl_xor(vd, m); }
            if (o == 0) {
                e1s[(size_t)(b * NHEAD + h) * NN + n] = vs;
                e1d[(size_t)(b * NHEAD + h) * NN + n] = vd;
            }
        }
    }
    gg.sync();

    // ---------- phase 3: layer-1 sparse softmax + aggregate + ELU (wave per row, no barriers) ----------
    for (int row = blockIdx.x * 8 + wv; row < NB * NN; row += GRID * 8) {
        int b = row / NN, n = row - b * NN;
        int K = cnt[row];
        for (int k = lane; k < K; k += 64) sm.a1.nb[wv][k] = nbr[(size_t)row * MAXK + k];
        for (int h = 0; h < NHEAD; ++h) {
            float es = e1s[(size_t)(b * NHEAD + h) * NN + n];
            const float* ed = e1d + (size_t)(b * NHEAD + h) * NN;
            float m = -1e30f;
            for (int k = lane; k < K; k += 64) {
                float e = es + ed[sm.a1.nb[wv][k]];
                e = e > 0.f ? e : 0.2f * e;
                sm.a1.p[wv][h][k] = e;
                m = fmaxf(m, e);
            }
#pragma unroll
            for (int mm = 1; mm < 64; mm <<= 1) m = fmaxf(m, __shfl_xor(m, mm));
            float s = 0.f;
            for (int k = lane; k < K; k += 64) {
                float v = __expf(sm.a1.p[wv][h][k] - m);
                sm.a1.p[wv][h][k] = v;
                s += v;
            }
#pragma unroll
            for (int mm = 1; mm < 64; mm <<= 1) s += __shfl_xor(s, mm);
            if (lane == 0) sm.a1.inv[wv][h] = 1.f / s;
        }
#pragma unroll
        for (int r = 0; r < 2; ++r) {
            int oi = r * 64 + lane;
            int h = oi >> 4, o = oi & 15;
            const float* hp = h1p + (size_t)(b * NHEAD + h) * NN * HHID + o;
            const float* pp = sm.a1.p[wv][h];
            const int* nbp = sm.a1.nb[wv];
            float acc = 0.f;
            int k = 0;
            for (; k + 4 <= K; k += 4) {
                float p0 = pp[k], p1 = pp[k + 1], p2 = pp[k + 2], p3 = pp[k + 3];
                int m0 = nbp[k], m1 = nbp[k + 1], m2 = nbp[k + 2], m3 = nbp[k + 3];
                acc += p0 * hp[(size_t)m0 * HHID] + p1 * hp[(size_t)m1 * HHID]
                     + p2 * hp[(size_t)m2 * HHID] + p3 * hp[(size_t)m3 * HHID];
            }
            for (; k < K; ++k) acc += pp[k] * hp[(size_t)nbp[k] * HHID];
            acc *= sm.a1.inv[wv][h];
            float v = acc > 0.f ? acc : expm1f(acc);    // ELU
            h1cat[(size_t)row * 128 + oi] = v;
        }
    }
    gg.sync();

    // ---------- phase 4: layer-2 projection + e_src2/e_dst2 (no barriers; full-K dot in regs) ----------
    {
        int g = t >> 7, gl = t & 127;
        int unit = blockIdx.x * 4 + g;
        int b = unit >> 5, chunk = unit & 31;
        int s = gl >> 6, o = gl & 63;             // s = wave within group -> uniform n per wave
        float wreg2[128];
#pragma unroll
        for (int j = 0; j < 128; ++j) wreg2[j] = w2[j * 64 + o];
        float as_r = as2[o], ad_r = ad2[o];
        for (int i = 0; i < 8; ++i) {
            int n = chunk * 16 + i * 2 + s;
            if (n < NN) {
                const float4* hp4 = (const float4*)(h1cat + (size_t)(b * NN + n) * 128);
                float a0 = 0.f, a1 = 0.f, a2 = 0.f, a3 = 0.f;
#pragma unroll
                for (int j4 = 0; j4 < 32; j4 += 4) {
                    float4 u0 = hp4[j4], u1 = hp4[j4 + 1], u2 = hp4[j4 + 2], u3 = hp4[j4 + 3];
                    a0 += u0.x * wreg2[j4 * 4] + u0.y * wreg2[j4 * 4 + 1] + u0.z * wreg2[j4 * 4 + 2] + u0.w * wreg2[j4 * 4 + 3];
                    a1 += u1.x * wreg2[j4 * 4 + 4] + u1.y * wreg2[j4 * 4 + 5] + u1.z * wreg2[j4 * 4 + 6] + u1.w * wreg2[j4 * 4 + 7];
                    a2 += u2.x * wreg2[j4 * 4 + 8] + u2.y * wreg2[j4 * 4 + 9] + u2.z * wreg2[j4 * 4 + 10] + u2.w * wreg2[j4 * 4 + 11];
                    a3 += u3.x * wreg2[j4 * 4 + 12] + u3.y * wreg2[j4 * 4 + 13] + u3.z * wreg2[j4 * 4 + 14] + u3.w * wreg2[j4 * 4 + 15];
                }
                float acc = (a0 + a1) + (a2 + a3);
                h2p[(size_t)(b * NN + n) * 64 + o] = acc;
                float vs = acc * as_r, vd = acc * ad_r;
#pragma unroll
                for (int m = 1; m < 64; m <<= 1) { vs += __shfl_xor(vs, m); vd += __shfl_xor(vd, m); }
                if (o == 0) { e2s[b * NN + n] = vs; e2d[b * NN + n] = vd; }
            }
        }
    }
    gg.sync();

    // ---------- phase 5: layer-2 sparse softmax + aggregate + fused score dots (wave per row) ----------
    for (int row = blockIdx.x * 8 + wv; row < NB * NN; row += GRID * 8) {
        int b = row / NN, n = row - b * NN;
        if (n >= NVALID) { xc[(size_t)row * 64 + lane] = 0.f; continue; }   // padded rows exactly 0
        int K = cnt[row];
        const int* nbg = nbr + (size_t)row * MAXK;
        int i0 = (lane < K) ? nbg[lane] : 0;
        int i1 = (lane + 64 < K) ? nbg[lane + 64] : 0;
        sm.a2.nb[wv][lane] = i0; sm.a2.nb[wv][lane + 64] = i1;
        float es = e2s[row];
        const float* ed = e2d + b * NN;
        float e0 = -1e30f, e1v = -1e30f;
        if (lane < K)      { float e = es + ed[i0]; e0 = e > 0.f ? e : 0.2f * e; }
        if (lane + 64 < K) { float e = es + ed[i1]; e1v = e > 0.f ? e : 0.2f * e; }
        float m = fmaxf(e0, e1v);
#pragma unroll
        for (int mm = 1; mm < 64; mm <<= 1) m = fmaxf(m, __shfl_xor(m, mm));
        float s0 = (lane < K) ? __expf(e0 - m) : 0.f;
        float s1 = (lane + 64 < K) ? __expf(e1v - m) : 0.f;
        float ss = s0 + s1;
#pragma unroll
        for (int mm = 1; mm < 64; mm <<= 1) ss += __shfl_xor(ss, mm);
        float inv = 1.f / ss;
        sm.a2.p[wv][lane] = s0 * inv; sm.a2.p[wv][lane + 64] = s1 * inv;
        const float* h2b = h2p + (size_t)b * NN * 64 + lane;
        const float* pp = sm.a2.p[wv];
        const int* nbp = sm.a2.nb[wv];
        float acc = 0.f;
        int k = 0;
        for (; k + 4 <= K; k += 4) {
            float p0 = pp[k], p1 = pp[k + 1], p2 = pp[k + 2], p3 = pp[k + 3];
            int m0 = nbp[k], m1 = nbp[k + 1], m2 = nbp[k + 2], m3 = nbp[k + 3];
            acc += p0 * h2b[(size_t)m0 * 64] + p1 * h2b[(size_t)m1 * 64]
                 + p2 * h2b[(size_t)m2 * 64] + p3 * h2b[(size_t)m3 * 64];
        }
        for (; k < K; ++k) acc += pp[k] * h2b[(size_t)nbp[k] * 64];
        xc[(size_t)row * 64 + lane] = acc;
        float v = acc * aw[lane];
#pragma unroll
        for (int mm = 1; mm < 64; mm <<= 1) v += __shfl_xor(v, mm);
        if (lane == 0) sc[row] = v;
        if (n == 0) {
            float v2 = acc * aw[64 + lane];
#pragma unroll
            for (int mm = 1; mm < 64; mm <<= 1) v2 += __shfl_xor(v2, mm);
            if (lane == 0) rootd[b] = v2;
        }
    }
    gg.sync();

    // ---------- phase 6: node softmax + pooled output (blocks 0..31) ----------
    if (blockIdx.x < NB) {
        int b = blockIdx.x;
        const float* xb = xc + (size_t)b * NN * 64;
        float rd = rootd[b];
        float s = NEG_INF;
        if (t < NVALID) {
            s = sc[b * NN + t] + rd;
            if (s == 0.f) s = NEG_INF;            // masked_fill(score==0)
        }
        float mx = s;
#pragma unroll
        for (int mm = 1; mm < 64; mm <<= 1) mx = fmaxf(mx, __shfl_xor(mx, mm));
        if (lane == 0) sm.pl.red[wv] = mx;
        __syncthreads();
        mx = sm.pl.red[0];
#pragma unroll
        for (int i = 1; i < 8; ++i) mx = fmaxf(mx, sm.pl.red[i]);
        float e = (t < NN) ? __expf(s - mx) : 0.f;
        float sum = e;
#pragma unroll
        for (int mm = 1; mm < 64; mm <<= 1) sum += __shfl_xor(sum, mm);
        __syncthreads();
        if (lane == 0) sm.pl.red[wv] = sum;
        __syncthreads();
        sum = 0.f;
#pragma unroll
        for (int i = 0; i < 8; ++i) sum += sm.pl.red[i];
        float inv = 1.f / sum;
        if (t < NN) {
            float a = e * inv;
            out[NB * HIN + b * NN + t] = a;       // attn output
            sm.pl.attn[t] = a;
        }
        __syncthreads();
        float acc = 0.f;
        for (int n2 = wv; n2 < NN; n2 += 8) acc += sm.pl.attn[n2] * xb[(size_t)n2 * 64 + lane];
        sm.pl.part[wv][lane] = acc;
        __syncthreads();
        if (t < 64) {
            float v = 0.f;
#pragma unroll
            for (int i = 0; i < 8; ++i) v += sm.pl.part[i][t];
            out[b * 64 + t] = v;                  // pooled output
        }
    }
}

extern "C" void kernel_launch(void* const* d_in, const int* in_sizes, int n_in,
                              void* d_out, int out_size, void* d_ws, size_t ws_size,
                              hipStream_t stream) {
    const float* x   = (const float*)d_in[0];
    const float* A   = (const float*)d_in[1];
    const float* w1  = (const float*)d_in[4];
    const float* as1 = (const float*)d_in[5];
    const float* ad1 = (const float*)d_in[6];
    const float* w2  = (const float*)d_in[7];
    const float* as2 = (const float*)d_in[8];
    const float* ad2 = (const float*)d_in[9];
    const float* aw  = (const float*)d_in[10];
    float* out = (float*)d_out;

    char* ws = (char*)d_ws;
    int* nbr = (int*)ws;                               // [16000][128]
    int* cnt = (int*)(ws + (size_t)16000 * 128 * 4);   // [16000]
    float* f = (float*)(ws + (size_t)16000 * 129 * 4);
    float* h1p   = f;  f += (size_t)NB * NHEAD * NN * HHID;
    float* e1s   = f;  f += (size_t)NB * NHEAD * NN;
    float* e1d   = f;  f += (size_t)NB * NHEAD * NN;
    float* h1cat = f;  f += (size_t)NB * NN * 128;
    float* h2p   = f;  f += (size_t)NB * NN * 64;
    float* e2s   = f;  f += (size_t)NB * NN;
    float* e2d   = f;  f += (size_t)NB * NN;
    float* xc    = f;  f += (size_t)NB * NN * 64;
    float* sc    = f;  f += (size_t)NB * NN;
    float* rootd = f;  f += NB;

    void* args[] = { (void*)&x, (void*)&A, (void*)&w1, (void*)&as1, (void*)&ad1,
                     (void*)&w2, (void*)&as2, (void*)&ad2, (void*)&aw,
                     (void*)&nbr, (void*)&cnt, (void*)&h1p, (void*)&e1s, (void*)&e1d,
                     (void*)&h1cat, (void*)&h2p, (void*)&e2s, (void*)&e2d,
                     (void*)&xc, (void*)&sc, (void*)&rootd, (void*)&out };
    hipLaunchCooperativeKernel((const void*)k_fused, dim3(GRID), dim3(BLK), args, 0, stream);
}